// Round 4
// baseline (431.744 us; speedup 1.0000x reference)
//
#include <hip/hip_runtime.h>
#include <math.h>

// PathFusionEmbedding: B=512, T=100, L=256, D=128, DEPTH=8 (P=9).
// Tree-structured LSTM: one step per tree node (heap indexing, parent = m>>1).
// Levels 0..4: single fused per-tree kernel (fp32, all state in LDS).
// Levels 5..8: split-bf16 MFMA kernel (h*W = hh*Wh + hh*Wl + hl*Wh; x*W
// single-term bf16), 64/32-node tiles, gate-halves across blockIdx.y,
// explicit B double-buffer prefetch from L2.

#define B_N 512
#define T_N 100
#define L_N 256
#define D_N 128
#define NPT 511

typedef __attribute__((ext_vector_type(8))) short short8;
typedef __attribute__((ext_vector_type(4))) float f32x4;
typedef __attribute__((ext_vector_type(4))) unsigned short ushort4v;

__device__ __forceinline__ unsigned short f2bf(float f) {
    unsigned u = __float_as_uint(f);
    return (unsigned short)((u + 0x7FFFu + ((u >> 16) & 1u)) >> 16);
}
__device__ __forceinline__ float bf2f(unsigned short b) {
    return __uint_as_float(((unsigned)b) << 16);
}
__device__ __forceinline__ float fsigmoid(float x) {
    return __builtin_amdgcn_rcpf(1.f + __builtin_amdgcn_exp2f(-1.44269504f * x));
}
__device__ __forceinline__ float ftanh(float x) {
    return 1.f - 2.f * __builtin_amdgcn_rcpf(1.f + __builtin_amdgcn_exp2f(2.88539009f * x));
}
__device__ __forceinline__ float dot4(float4 a, float4 b) {
    return a.x * b.x + a.y * b.y + a.z * b.z + a.w * b.w;
}

// ---------------- weight pack + bias prep ----------------
// W'[n'][k] = k<128 ? w_ih[n'][k] : w_hh[n'][k-128]   (n' = gate*128 + j)
// B-fragment order: kb=k>>5, krel=k&31, quad=krel>>3, e=krel&7, tn=n'>>4,
// lane=quad*16+(n'&15); Bhi[((kb*32+tn)*64+lane)*8+e]. Blo for k>=128 only.
__global__ __launch_bounds__(256) void pack_kernel(const float* __restrict__ w_ih,
                                                   const float* __restrict__ w_hh,
                                                   const float* __restrict__ b_ih,
                                                   const float* __restrict__ b_hh,
                                                   unsigned short* __restrict__ Bhi,
                                                   unsigned short* __restrict__ Blo,
                                                   float* __restrict__ bias) {
    const int idx = blockIdx.x * 256 + threadIdx.x;   // 131072 = 512 n' x 256 k
    const int k  = idx & 255;
    const int np = idx >> 8;
    const float val = (k < 128) ? w_ih[(size_t)np * 128 + k]
                                : w_hh[(size_t)np * 128 + (k - 128)];
    const unsigned short hi = f2bf(val);
    const int kb = k >> 5, krel = k & 31, quad = krel >> 3, e = krel & 7;
    const int tn = np >> 4, col = np & 15, lane = quad * 16 + col;
    Bhi[(((size_t)kb * 32 + tn) * 64 + lane) * 8 + e] = hi;
    if (kb >= 4) {
        const unsigned short lo = f2bf(val - bf2f(hi));
        Blo[((((size_t)kb - 4) * 32 + tn) * 64 + lane) * 8 + e] = lo;
    }
    if (k == 0) bias[np] = b_ih[np] + b_hh[np];
}

// ---------------- leaf extraction ----------------
__global__ __launch_bounds__(256) void leaf_kernel(const float* __restrict__ cross,
                                                   int* __restrict__ leaf) {
    const int row  = blockIdx.x * 4 + (threadIdx.x >> 6);
    const int lane = threadIdx.x & 63;
    const float4 v = reinterpret_cast<const float4*>(cross + (size_t)row * L_N)[lane];
    int idx = -1;
    if      (v.x > 0.f) idx = lane * 4 + 0;
    else if (v.y > 0.f) idx = lane * 4 + 1;
    else if (v.z > 0.f) idx = lane * 4 + 2;
    else if (v.w > 0.f) idx = lane * 4 + 3;
    const unsigned long long m = __ballot(idx >= 0);
    if (m == 0ULL) {
        if (lane == 0) leaf[row] = -1;
    } else {
        const int first = __builtin_ctzll(m);
        if (lane == first) leaf[row] = idx;
    }
}

// ---------------- fused small levels 0..4, one block per tree ----------------
// 512 threads: j = tid&127, grp = tid>>7 (node stripe m = grp + 4*s).
// All h/c state lives in LDS; only level-4 h,c go to global (for d=5 MFMA).
__global__ __launch_bounds__(512) void small_levels_kernel(
    const float* __restrict__ node_emb,
    const float* __restrict__ w_ih,
    const float* __restrict__ w_hh,
    const float* __restrict__ b_ih,
    const float* __restrict__ b_hh,
    float* __restrict__ h4,
    float* __restrict__ c4)
{
    __shared__ float xb[16 * 128];        // x rows for current level (max 16)
    __shared__ float hb[2][16 * 128];
    __shared__ float cb[2][16 * 128];
    __shared__ float bs[512];

    const int t   = blockIdx.x;
    const int tid = threadIdx.x;
    const int j   = tid & 127;
    const int grp = tid >> 7;             // 0..3

    if (tid < 512) { /* always true; keep uniform */ }
    for (int u = tid; u < 512; u += 512) bs[u] = b_ih[u] + b_hh[u];

    for (int d = 0; d <= 4; ++d) {
        const int M = 1 << d;
        __syncthreads();
        // stage x rows: M*32 float4s
        for (int u = tid; u < M * 32; u += 512) {
            const int m = u >> 5, c4i = u & 31;
            const int local = M - 1 + m;
            reinterpret_cast<float4*>(&xb[m * 128])[c4i] =
                reinterpret_cast<const float4*>(
                    node_emb + (size_t)(t * NPT + local) * D_N)[c4i];
        }
        __syncthreads();

        const int cur = d & 1, prv = cur ^ 1;
        float acc[4][4];
        #pragma unroll
        for (int s = 0; s < 4; ++s)
            #pragma unroll
            for (int g = 0; g < 4; ++g) acc[s][g] = 0.f;

        // x-part
        const float* wi = w_ih + (size_t)(j)       * D_N;
        const float* wf = w_ih + (size_t)(128 + j) * D_N;
        const float* wg = w_ih + (size_t)(256 + j) * D_N;
        const float* wo = w_ih + (size_t)(384 + j) * D_N;
        for (int kc = 0; kc < 32; ++kc) {
            const float4 a = reinterpret_cast<const float4*>(wi)[kc];
            const float4 b = reinterpret_cast<const float4*>(wf)[kc];
            const float4 c = reinterpret_cast<const float4*>(wg)[kc];
            const float4 e = reinterpret_cast<const float4*>(wo)[kc];
            #pragma unroll
            for (int s = 0; s < 4; ++s) {
                const int m = grp + 4 * s;
                if (m < M) {
                    const float4 xv = *reinterpret_cast<const float4*>(&xb[m * 128 + kc * 4]);
                    acc[s][0] += dot4(a, xv);
                    acc[s][1] += dot4(b, xv);
                    acc[s][2] += dot4(c, xv);
                    acc[s][3] += dot4(e, xv);
                }
            }
        }
        // h-part
        if (d > 0) {
            const float* vi = w_hh + (size_t)(j)       * D_N;
            const float* vf = w_hh + (size_t)(128 + j) * D_N;
            const float* vg = w_hh + (size_t)(256 + j) * D_N;
            const float* vo = w_hh + (size_t)(384 + j) * D_N;
            for (int kc = 0; kc < 32; ++kc) {
                const float4 a = reinterpret_cast<const float4*>(vi)[kc];
                const float4 b = reinterpret_cast<const float4*>(vf)[kc];
                const float4 c = reinterpret_cast<const float4*>(vg)[kc];
                const float4 e = reinterpret_cast<const float4*>(vo)[kc];
                #pragma unroll
                for (int s = 0; s < 4; ++s) {
                    const int m = grp + 4 * s;
                    if (m < M) {
                        const float4 hv = *reinterpret_cast<const float4*>(
                            &hb[prv][(m >> 1) * 128 + kc * 4]);
                        acc[s][0] += dot4(a, hv);
                        acc[s][1] += dot4(b, hv);
                        acc[s][2] += dot4(c, hv);
                        acc[s][3] += dot4(e, hv);
                    }
                }
            }
        }
        // epilogue
        #pragma unroll
        for (int s = 0; s < 4; ++s) {
            const int m = grp + 4 * s;
            if (m < M) {
                const float ig = fsigmoid(acc[s][0] + bs[j]);
                const float fg = fsigmoid(acc[s][1] + bs[128 + j]);
                const float gv = ftanh(acc[s][2] + bs[256 + j]);
                const float og = fsigmoid(acc[s][3] + bs[384 + j]);
                const float cp = (d > 0) ? cb[prv][(m >> 1) * 128 + j] : 0.f;
                const float cn = fg * cp + ig * gv;
                const float hn = og * ftanh(cn);
                hb[cur][m * 128 + j] = hn;
                cb[cur][m * 128 + j] = cn;
                if (d == 4) {
                    h4[(size_t)(t * 16 + m) * D_N + j] = hn;
                    c4[(size_t)(t * 16 + m) * D_N + j] = cn;
                }
            }
        }
    }
}

// ---------------- MFMA level kernel (d=5..8) ----------------
// Template MT: node tile = MT*16 (32 or 64). Block: 256 threads = 4 waves.
// blockIdx.y = gate-half; wave w handles idx = half*4+w, tn = g*8+idx
// (4 tn x MT mt tiles, <=64 AGPR). A staged fragment-major in LDS
// (conflict-free ds_read_b128). B explicitly double-buffer-prefetched from L2.
template<int MT>
__global__ __launch_bounds__(256, 2) void mfma_level_kernel(
    const float* __restrict__ node_emb,
    const unsigned short* __restrict__ Bhi,
    const unsigned short* __restrict__ Blo,
    const float* __restrict__ bias,
    const float* __restrict__ h_prev,
    const float* __restrict__ c_prev,
    float* __restrict__ h_cur,
    float* __restrict__ c_cur,
    const int d)
{
    constexpr int NB = MT * 16;
    __shared__ unsigned short AhiF[8 * MT * 512];   // [kb][mt][lane*8+e]
    __shared__ unsigned short AloF[4 * MT * 512];

    const int tid  = threadIdx.x;
    const int m0   = blockIdx.x * NB;
    const int half = blockIdx.y;

    // ---- stage A (both halves stage full A) ----
    {
        const int tpr = 256 / NB;            // threads per row
        const int r   = tid / tpr;
        const int q   = tid % tpr;
        const int gm  = m0 + r;
        const int mt  = r >> 4, ml = r & 15;
        const int t     = gm >> d;
        const int p     = gm - (t << d);
        const int local = (1 << d) - 1 + p;
        const float* xrow = node_emb + (size_t)(t * NPT + local) * D_N;
        const float* hrow = h_prev + (size_t)(gm >> 1) * D_N;
        #pragma unroll
        for (int i = 0; i < NB / 4; ++i) {
            const int k   = q * NB + i * 4;
            const int kb  = k >> 5;
            const int qk  = (k & 31) >> 3;
            const int e0  = k & 4;
            const float4 v = (k < 128)
                ? reinterpret_cast<const float4*>(xrow)[k >> 2]
                : reinterpret_cast<const float4*>(hrow)[(k - 128) >> 2];
            const ushort4v hv = { f2bf(v.x), f2bf(v.y), f2bf(v.z), f2bf(v.w) };
            *reinterpret_cast<ushort4v*>(
                &AhiF[((kb * MT + mt) * 64 + qk * 16 + ml) * 8 + e0]) = hv;
            if (k >= 128) {
                const ushort4v lv = { f2bf(v.x - bf2f(hv.x)), f2bf(v.y - bf2f(hv.y)),
                                      f2bf(v.z - bf2f(hv.z)), f2bf(v.w - bf2f(hv.w)) };
                *reinterpret_cast<ushort4v*>(
                    &AloF[(((kb - 4) * MT + mt) * 64 + qk * 16 + ml) * 8 + e0]) = lv;
            }
        }
    }
    __syncthreads();

    const int w    = tid >> 6;
    const int lane = tid & 63;
    const int ml   = lane & 15;
    const int quad = lane >> 4;
    const int idx  = half * 4 + w;          // 0..7

    f32x4 acc[MT][4];                        // [mt][gate]
    #pragma unroll
    for (int mt = 0; mt < MT; ++mt)
        #pragma unroll
        for (int g = 0; g < 4; ++g) acc[mt][g] = (f32x4)0.f;

    const short8* Bh8 = reinterpret_cast<const short8*>(Bhi);
    const short8* Bl8 = reinterpret_cast<const short8*>(Blo);
    const short8* Ah8 = reinterpret_cast<const short8*>(AhiF);
    const short8* Al8 = reinterpret_cast<const short8*>(AloF);

    short8 bh[4], bl[4];
    #pragma unroll
    for (int g = 0; g < 4; ++g)
        bh[g] = Bh8[(0 * 32 + g * 8 + idx) * 64 + lane];

    #pragma unroll
    for (int kb = 0; kb < 8; ++kb) {
        short8 bhn[4], bln[4];
        // prefetch next-kb B before issuing this kb's MFMAs
        if (kb < 7) {
            #pragma unroll
            for (int g = 0; g < 4; ++g)
                bhn[g] = Bh8[((kb + 1) * 32 + g * 8 + idx) * 64 + lane];
            if (kb + 1 >= 4) {
                #pragma unroll
                for (int g = 0; g < 4; ++g)
                    bln[g] = Bl8[((kb + 1 - 4) * 32 + g * 8 + idx) * 64 + lane];
            }
        }
        short8 ah[MT], al[MT];
        #pragma unroll
        for (int mt = 0; mt < MT; ++mt)
            ah[mt] = Ah8[(kb * MT + mt) * 64 + lane];
        if (kb >= 4) {
            #pragma unroll
            for (int mt = 0; mt < MT; ++mt)
                al[mt] = Al8[((kb - 4) * MT + mt) * 64 + lane];
        }
        #pragma unroll
        for (int g = 0; g < 4; ++g) {
            #pragma unroll
            for (int mt = 0; mt < MT; ++mt) {
                acc[mt][g] = __builtin_amdgcn_mfma_f32_16x16x32_bf16(
                    ah[mt], bh[g], acc[mt][g], 0, 0, 0);
                if (kb >= 4) {
                    acc[mt][g] = __builtin_amdgcn_mfma_f32_16x16x32_bf16(
                        ah[mt], bl[g], acc[mt][g], 0, 0, 0);
                    acc[mt][g] = __builtin_amdgcn_mfma_f32_16x16x32_bf16(
                        al[mt], bh[g], acc[mt][g], 0, 0, 0);
                }
            }
        }
        #pragma unroll
        for (int g = 0; g < 4; ++g) { bh[g] = bhn[g]; bl[g] = bln[g]; }
    }

    // ---- fused LSTM epilogue (C/D: row = quad*4+r -> node, col = ml -> j) ----
    const int j  = idx * 16 + ml;
    const float bi = bias[j];
    const float bf = bias[128 + j];
    const float bg = bias[256 + j];
    const float bo = bias[384 + j];
    #pragma unroll
    for (int mt = 0; mt < MT; ++mt) {
        #pragma unroll
        for (int r = 0; r < 4; ++r) {
            const int m = m0 + mt * 16 + quad * 4 + r;
            const float ig = fsigmoid(acc[mt][0][r] + bi);
            const float fg = fsigmoid(acc[mt][1][r] + bf);
            const float gv = ftanh(acc[mt][2][r] + bg);
            const float og = fsigmoid(acc[mt][3][r] + bo);
            const float cp = c_prev[(size_t)(m >> 1) * D_N + j];
            const float cn = fg * cp + ig * gv;
            const float hn = og * ftanh(cn);
            c_cur[(size_t)m * D_N + j] = cn;
            h_cur[(size_t)m * D_N + j] = hn;
        }
    }
}

// ---------------- final gather ----------------
__global__ __launch_bounds__(256) void gather_kernel(const float* __restrict__ h8,
                                                     const int* __restrict__ leaf,
                                                     float* __restrict__ out) {
    const int idx = blockIdx.x * 256 + threadIdx.x;
    const int k4  = idx & 31;
    const int bt  = idx >> 5;
    const int t   = bt % T_N;
    const int lf  = leaf[bt];
    float4 v = make_float4(0.f, 0.f, 0.f, 0.f);
    if (lf >= 0)
        v = reinterpret_cast<const float4*>(h8 + (size_t)(t * L_N + lf) * D_N)[k4];
    reinterpret_cast<float4*>(out)[idx] = v;
}

extern "C" void kernel_launch(void* const* d_in, const int* in_sizes, int n_in,
                              void* d_out, int out_size, void* d_ws, size_t ws_size,
                              hipStream_t stream) {
    const float* cross    = (const float*)d_in[0];
    const float* node_emb = (const float*)d_in[1];
    const float* w_ih     = (const float*)d_in[2];
    const float* w_hh     = (const float*)d_in[3];
    const float* b_ih     = (const float*)d_in[4];
    const float* b_hh     = (const float*)d_in[5];
    float* out = (float*)d_out;
    float* ws  = (float*)d_ws;

    // ws layout (floats): hA/cA (even levels), hB/cB (odd), leaf, bias, Bhi, Blo
    const size_t SA = (size_t)25600 * D_N;
    const size_t SB = (size_t)12800 * D_N;
    float* hA = ws;
    float* cA = hA + SA;
    float* hB = cA + SA;
    float* cB = hB + SB;
    int*   leaf = (int*)(cB + SB);
    float* bias = (float*)(leaf + 51200);
    unsigned short* Bhi = (unsigned short*)(bias + 512);
    unsigned short* Blo = Bhi + 131072;

    pack_kernel<<<512, 256, 0, stream>>>(w_ih, w_hh, b_ih, b_hh, Bhi, Blo, bias);
    leaf_kernel<<<(B_N * T_N) / 4, 256, 0, stream>>>(cross, leaf);

    // levels 0..4 fused (level 4 -> hA/cA at rows t*16+p)
    small_levels_kernel<<<T_N, 512, 0, stream>>>(node_emb, w_ih, w_hh, b_ih, b_hh,
                                                 hA, cA);

    // levels 5..8: MFMA split-bf16 (odd d -> B buffers, even d -> A buffers)
    for (int d = 5; d <= 8; ++d) {
        const int M = T_N << d;
        float* hc = (d & 1) ? hB : hA;
        float* cc = (d & 1) ? cB : cA;
        float* hp = (d & 1) ? hA : hB;
        float* cp = (d & 1) ? cA : cB;
        if (d <= 6) {
            dim3 grid(M / 32, 2);
            mfma_level_kernel<2><<<grid, 256, 0, stream>>>(node_emb, Bhi, Blo, bias,
                                                           hp, cp, hc, cc, d);
        } else {
            dim3 grid(M / 64, 2);
            mfma_level_kernel<4><<<grid, 256, 0, stream>>>(node_emb, Bhi, Blo, bias,
                                                           hp, cp, hc, cc, d);
        }
    }
    // d=8 wrote hA
    gather_kernel<<<(B_N * T_N * (D_N / 4)) / 256, 256, 0, stream>>>(hA, leaf, out);
}

// Round 5
// 255.014 us; speedup vs baseline: 1.6930x; 1.6930x over previous
//
#include <hip/hip_runtime.h>
#include <math.h>

// PathFusionEmbedding: B=512, T=100, L=256, D=128, DEPTH=8 (P=9).
// Tree-structured LSTM: one step per tree node (heap indexing, parent = m>>1).
// ALL levels 0..8 run through one split-bf16 MFMA kernel
// (h*W = hh*Wh + hh*Wl + hl*Wh; x*W single-term bf16 -> fp32-grade accuracy):
// M-guarded for ragged levels, root(d=0) stages zero h. B weights pre-packed
// in fragment order, L2-resident, double-buffer prefetched.
// Leaf extraction fused into the final gather (one wave per (b,t) row).

#define B_N 512
#define T_N 100
#define L_N 256
#define D_N 128
#define NPT 511

typedef __attribute__((ext_vector_type(8))) short short8;
typedef __attribute__((ext_vector_type(4))) float f32x4;
typedef __attribute__((ext_vector_type(4))) unsigned short ushort4v;

__device__ __forceinline__ unsigned short f2bf(float f) {
    unsigned u = __float_as_uint(f);
    return (unsigned short)((u + 0x7FFFu + ((u >> 16) & 1u)) >> 16);
}
__device__ __forceinline__ float bf2f(unsigned short b) {
    return __uint_as_float(((unsigned)b) << 16);
}
__device__ __forceinline__ float fsigmoid(float x) {
    return __builtin_amdgcn_rcpf(1.f + __builtin_amdgcn_exp2f(-1.44269504f * x));
}
__device__ __forceinline__ float ftanh(float x) {
    return 1.f - 2.f * __builtin_amdgcn_rcpf(1.f + __builtin_amdgcn_exp2f(2.88539009f * x));
}

// ---------------- weight pack + bias prep ----------------
// W'[n'][k] = k<128 ? w_ih[n'][k] : w_hh[n'][k-128]   (n' = gate*128 + j)
// B-fragment order: kb=k>>5, krel=k&31, quad=krel>>3, e=krel&7, tn=n'>>4,
// lane=quad*16+(n'&15); Bhi[((kb*32+tn)*64+lane)*8+e]. Blo for k>=128 only.
__global__ __launch_bounds__(256) void pack_kernel(const float* __restrict__ w_ih,
                                                   const float* __restrict__ w_hh,
                                                   const float* __restrict__ b_ih,
                                                   const float* __restrict__ b_hh,
                                                   unsigned short* __restrict__ Bhi,
                                                   unsigned short* __restrict__ Blo,
                                                   float* __restrict__ bias) {
    const int idx = blockIdx.x * 256 + threadIdx.x;   // 131072 = 512 n' x 256 k
    const int k  = idx & 255;
    const int np = idx >> 8;
    const float val = (k < 128) ? w_ih[(size_t)np * 128 + k]
                                : w_hh[(size_t)np * 128 + (k - 128)];
    const unsigned short hi = f2bf(val);
    const int kb = k >> 5, krel = k & 31, quad = krel >> 3, e = krel & 7;
    const int tn = np >> 4, col = np & 15, lane = quad * 16 + col;
    Bhi[(((size_t)kb * 32 + tn) * 64 + lane) * 8 + e] = hi;
    if (kb >= 4) {
        const unsigned short lo = f2bf(val - bf2f(hi));
        Blo[((((size_t)kb - 4) * 32 + tn) * 64 + lane) * 8 + e] = lo;
    }
    if (k == 0) bias[np] = b_ih[np] + b_hh[np];
}

// ---------------- MFMA level kernel (all levels d=0..8) ----------------
// Template MT: node tile = MT*16 (32 or 64). Block: 256 threads = 4 waves.
// blockIdx.y = gate-half; wave w handles idx = half*4+w, tn = g*8+idx
// (4 tn x MT mt tiles, <=64 AGPR). A staged fragment-major in LDS
// (conflict-free ds_read_b128). B double-buffer-prefetched from L2.
// Ragged M: staged rows clamped to M-1, stores guarded. d=0: h-half of A
// staged as zeros, cp=0.
template<int MT>
__global__ __launch_bounds__(256, 2) void mfma_level_kernel(
    const float* __restrict__ node_emb,
    const unsigned short* __restrict__ Bhi,
    const unsigned short* __restrict__ Blo,
    const float* __restrict__ bias,
    const float* __restrict__ h_prev,
    const float* __restrict__ c_prev,
    float* __restrict__ h_cur,
    float* __restrict__ c_cur,
    const int d, const int M)
{
    constexpr int NB = MT * 16;
    __shared__ unsigned short AhiF[8 * MT * 512];   // [kb][mt][lane*8+e]
    __shared__ unsigned short AloF[4 * MT * 512];

    const int tid  = threadIdx.x;
    const int m0   = blockIdx.x * NB;
    const int half = blockIdx.y;
    const bool root = (d == 0);

    // ---- stage A (both halves stage full A) ----
    {
        const int tpr = 256 / NB;            // threads per row
        const int r   = tid / tpr;
        const int q   = tid % tpr;
        int gm = m0 + r;
        if (gm > M - 1) gm = M - 1;          // clamp: duplicate last row
        const int mt  = r >> 4, ml = r & 15;
        const int t     = gm >> d;
        const int p     = gm - (t << d);
        const int local = (1 << d) - 1 + p;
        const float* xrow = node_emb + (size_t)(t * NPT + local) * D_N;
        const float* hrow = root ? xrow : (h_prev + (size_t)(gm >> 1) * D_N);
        const float4 z4 = make_float4(0.f, 0.f, 0.f, 0.f);
        #pragma unroll
        for (int i = 0; i < NB / 4; ++i) {
            const int k   = q * NB + i * 4;
            const int kb  = k >> 5;
            const int qk  = (k & 31) >> 3;
            const int e0  = k & 4;
            float4 v;
            if (k < 128)      v = reinterpret_cast<const float4*>(xrow)[k >> 2];
            else if (root)    v = z4;
            else              v = reinterpret_cast<const float4*>(hrow)[(k - 128) >> 2];
            const ushort4v hv = { f2bf(v.x), f2bf(v.y), f2bf(v.z), f2bf(v.w) };
            *reinterpret_cast<ushort4v*>(
                &AhiF[((kb * MT + mt) * 64 + qk * 16 + ml) * 8 + e0]) = hv;
            if (k >= 128) {
                const ushort4v lv = { f2bf(v.x - bf2f(hv.x)), f2bf(v.y - bf2f(hv.y)),
                                      f2bf(v.z - bf2f(hv.z)), f2bf(v.w - bf2f(hv.w)) };
                *reinterpret_cast<ushort4v*>(
                    &AloF[(((kb - 4) * MT + mt) * 64 + qk * 16 + ml) * 8 + e0]) = lv;
            }
        }
    }
    __syncthreads();

    const int w    = tid >> 6;
    const int lane = tid & 63;
    const int ml   = lane & 15;
    const int quad = lane >> 4;
    const int idx  = half * 4 + w;          // 0..7

    f32x4 acc[MT][4];                        // [mt][gate]
    #pragma unroll
    for (int mt = 0; mt < MT; ++mt)
        #pragma unroll
        for (int g = 0; g < 4; ++g) acc[mt][g] = (f32x4)0.f;

    const short8* Bh8 = reinterpret_cast<const short8*>(Bhi);
    const short8* Bl8 = reinterpret_cast<const short8*>(Blo);
    const short8* Ah8 = reinterpret_cast<const short8*>(AhiF);
    const short8* Al8 = reinterpret_cast<const short8*>(AloF);

    short8 bh[4], bl[4];
    #pragma unroll
    for (int g = 0; g < 4; ++g)
        bh[g] = Bh8[(0 * 32 + g * 8 + idx) * 64 + lane];

    #pragma unroll
    for (int kb = 0; kb < 8; ++kb) {
        short8 bhn[4], bln[4];
        // prefetch next-kb B before issuing this kb's MFMAs
        if (kb < 7) {
            #pragma unroll
            for (int g = 0; g < 4; ++g)
                bhn[g] = Bh8[((kb + 1) * 32 + g * 8 + idx) * 64 + lane];
            if (kb + 1 >= 4) {
                #pragma unroll
                for (int g = 0; g < 4; ++g)
                    bln[g] = Bl8[((kb + 1 - 4) * 32 + g * 8 + idx) * 64 + lane];
            }
        }
        short8 ah[MT], al[MT];
        #pragma unroll
        for (int mt = 0; mt < MT; ++mt)
            ah[mt] = Ah8[(kb * MT + mt) * 64 + lane];
        if (kb >= 4) {
            #pragma unroll
            for (int mt = 0; mt < MT; ++mt)
                al[mt] = Al8[((kb - 4) * MT + mt) * 64 + lane];
        }
        #pragma unroll
        for (int g = 0; g < 4; ++g) {
            #pragma unroll
            for (int mt = 0; mt < MT; ++mt) {
                acc[mt][g] = __builtin_amdgcn_mfma_f32_16x16x32_bf16(
                    ah[mt], bh[g], acc[mt][g], 0, 0, 0);
                if (kb >= 4) {
                    acc[mt][g] = __builtin_amdgcn_mfma_f32_16x16x32_bf16(
                        ah[mt], bl[g], acc[mt][g], 0, 0, 0);
                    acc[mt][g] = __builtin_amdgcn_mfma_f32_16x16x32_bf16(
                        al[mt], bh[g], acc[mt][g], 0, 0, 0);
                }
            }
        }
        #pragma unroll
        for (int g = 0; g < 4; ++g) {
            if (kb < 7) { bh[g] = bhn[g]; bl[g] = bln[g]; }
        }
    }

    // ---- fused LSTM epilogue (C/D: row = quad*4+r -> node, col = ml -> j) ----
    const int j  = idx * 16 + ml;
    const float bi = bias[j];
    const float bf = bias[128 + j];
    const float bg = bias[256 + j];
    const float bo = bias[384 + j];
    #pragma unroll
    for (int mt = 0; mt < MT; ++mt) {
        #pragma unroll
        for (int r = 0; r < 4; ++r) {
            const int m = m0 + mt * 16 + quad * 4 + r;
            if (m < M) {
                const float ig = fsigmoid(acc[mt][0][r] + bi);
                const float fg = fsigmoid(acc[mt][1][r] + bf);
                const float gv = ftanh(acc[mt][2][r] + bg);
                const float og = fsigmoid(acc[mt][3][r] + bo);
                const float cp = root ? 0.f : c_prev[(size_t)(m >> 1) * D_N + j];
                const float cn = fg * cp + ig * gv;
                const float hn = og * ftanh(cn);
                c_cur[(size_t)m * D_N + j] = cn;
                h_cur[(size_t)m * D_N + j] = hn;
            }
        }
    }
}

// ---------------- fused leaf-extract + gather ----------------
// One 64-lane wave per (b,t) row: ballot over the one-hot cross row -> leaf,
// then out[b,t,:] = active ? h8[t*256+leaf, :] : 0   (2 floats per lane).
__global__ __launch_bounds__(256) void gather_kernel(const float* __restrict__ cross,
                                                     const float* __restrict__ h8,
                                                     float* __restrict__ out) {
    const int bt   = blockIdx.x * 4 + (threadIdx.x >> 6);
    const int lane = threadIdx.x & 63;
    const int t    = bt % T_N;
    const float4 v = reinterpret_cast<const float4*>(cross + (size_t)bt * L_N)[lane];
    int idx = -1;
    if      (v.x > 0.f) idx = lane * 4 + 0;
    else if (v.y > 0.f) idx = lane * 4 + 1;
    else if (v.z > 0.f) idx = lane * 4 + 2;
    else if (v.w > 0.f) idx = lane * 4 + 3;
    const unsigned long long m = __ballot(idx >= 0);
    int lf = -1;
    if (m != 0ULL) {
        const int first = __builtin_ctzll(m);
        lf = __shfl(idx, first);
    }
    float2 o = make_float2(0.f, 0.f);
    if (lf >= 0)
        o = reinterpret_cast<const float2*>(h8 + (size_t)(t * L_N + lf) * D_N)[lane];
    reinterpret_cast<float2*>(out + (size_t)bt * D_N)[lane] = o;
}

extern "C" void kernel_launch(void* const* d_in, const int* in_sizes, int n_in,
                              void* d_out, int out_size, void* d_ws, size_t ws_size,
                              hipStream_t stream) {
    const float* cross    = (const float*)d_in[0];
    const float* node_emb = (const float*)d_in[1];
    const float* w_ih     = (const float*)d_in[2];
    const float* w_hh     = (const float*)d_in[3];
    const float* b_ih     = (const float*)d_in[4];
    const float* b_hh     = (const float*)d_in[5];
    float* out = (float*)d_out;
    float* ws  = (float*)d_ws;

    // ws layout (floats): hA/cA (even levels, <=25600 rows),
    // hB/cB (odd levels, <=12800 rows), bias, Bhi, Blo
    const size_t SA = (size_t)25600 * D_N;
    const size_t SB = (size_t)12800 * D_N;
    float* hA = ws;
    float* cA = hA + SA;
    float* hB = cA + SA;
    float* cB = hB + SB;
    float* bias = cB + SB;
    unsigned short* Bhi = (unsigned short*)(bias + 512);
    unsigned short* Blo = Bhi + 131072;

    pack_kernel<<<512, 256, 0, stream>>>(w_ih, w_hh, b_ih, b_hh, Bhi, Blo, bias);

    // all levels 0..8 via MFMA (even d -> A buffers, odd d -> B buffers)
    for (int d = 0; d <= 8; ++d) {
        const int M = T_N << d;
        float* hc = (d & 1) ? hB : hA;
        float* cc = (d & 1) ? cB : cA;
        float* hp = (d & 1) ? hA : hB;
        float* cp = (d & 1) ? cA : cB;
        if (d <= 6) {
            dim3 grid((M + 31) / 32, 2);
            mfma_level_kernel<2><<<grid, 256, 0, stream>>>(node_emb, Bhi, Blo, bias,
                                                           hp, cp, hc, cc, d, M);
        } else {
            dim3 grid((M + 63) / 64, 2);
            mfma_level_kernel<4><<<grid, 256, 0, stream>>>(node_emb, Bhi, Blo, bias,
                                                           hp, cp, hc, cc, d, M);
        }
    }
    // d=8 wrote hA; fused leaf+gather
    gather_kernel<<<(B_N * T_N) / 4, 256, 0, stream>>>(cross, hA, out);
}

// Round 6
// 241.990 us; speedup vs baseline: 1.7841x; 1.0538x over previous
//
#include <hip/hip_runtime.h>
#include <math.h>

// PathFusionEmbedding: B=512, T=100, L=256, D=128, DEPTH=8 (P=9).
// Tree-structured LSTM: one step per tree node (heap indexing, parent = m>>1).
// All levels via one split-bf16 MFMA kernel (h*W = hh*Wh + hh*Wl + hl*Wh;
// x*W single-term bf16 -> fp32-grade accuracy).
// R6: 512-thread / 8-wave blocks covering ALL 512 gates (no grid.y duplicate
// staging), MT=2 (32-node tile, 24 KB LDS) for max grid/occupancy, c_prev
// register-prefetched before the K-loop.

#define B_N 512
#define T_N 100
#define L_N 256
#define D_N 128
#define NPT 511

typedef __attribute__((ext_vector_type(8))) short short8;
typedef __attribute__((ext_vector_type(4))) float f32x4;
typedef __attribute__((ext_vector_type(4))) unsigned short ushort4v;

__device__ __forceinline__ unsigned short f2bf(float f) {
    unsigned u = __float_as_uint(f);
    return (unsigned short)((u + 0x7FFFu + ((u >> 16) & 1u)) >> 16);
}
__device__ __forceinline__ float bf2f(unsigned short b) {
    return __uint_as_float(((unsigned)b) << 16);
}
__device__ __forceinline__ float fsigmoid(float x) {
    return __builtin_amdgcn_rcpf(1.f + __builtin_amdgcn_exp2f(-1.44269504f * x));
}
__device__ __forceinline__ float ftanh(float x) {
    return 1.f - 2.f * __builtin_amdgcn_rcpf(1.f + __builtin_amdgcn_exp2f(2.88539009f * x));
}

// ---------------- weight pack + bias prep ----------------
// W'[n'][k] = k<128 ? w_ih[n'][k] : w_hh[n'][k-128]   (n' = gate*128 + j)
// B-fragment order: kb=k>>5, krel=k&31, quad=krel>>3, e=krel&7, tn=n'>>4,
// lane=quad*16+(n'&15); Bhi[((kb*32+tn)*64+lane)*8+e]. Blo for k>=128 only.
__global__ __launch_bounds__(256) void pack_kernel(const float* __restrict__ w_ih,
                                                   const float* __restrict__ w_hh,
                                                   const float* __restrict__ b_ih,
                                                   const float* __restrict__ b_hh,
                                                   unsigned short* __restrict__ Bhi,
                                                   unsigned short* __restrict__ Blo,
                                                   float* __restrict__ bias) {
    const int idx = blockIdx.x * 256 + threadIdx.x;   // 131072 = 512 n' x 256 k
    const int k  = idx & 255;
    const int np = idx >> 8;
    const float val = (k < 128) ? w_ih[(size_t)np * 128 + k]
                                : w_hh[(size_t)np * 128 + (k - 128)];
    const unsigned short hi = f2bf(val);
    const int kb = k >> 5, krel = k & 31, quad = krel >> 3, e = krel & 7;
    const int tn = np >> 4, col = np & 15, lane = quad * 16 + col;
    Bhi[(((size_t)kb * 32 + tn) * 64 + lane) * 8 + e] = hi;
    if (kb >= 4) {
        const unsigned short lo = f2bf(val - bf2f(hi));
        Blo[((((size_t)kb - 4) * 32 + tn) * 64 + lane) * 8 + e] = lo;
    }
    if (k == 0) bias[np] = b_ih[np] + b_hh[np];
}

// ---------------- MFMA level kernel (all levels d=0..8) ----------------
// Block: 512 threads = 8 waves; tile = NB=MT*16 nodes x all 512 gates.
// Wave w (=idx 0..7): tn = g*8 + idx, g=0..3; MT mt tiles -> 4*MT C-tiles.
// A staged fragment-major in LDS (conflict-free ds_read_b128).
// B double-buffer prefetched from L2. c_prev register-prefetched pre-K-loop.
// Ragged M: staged rows clamped, stores guarded. d=0 (root): h half zeroed.
template<int MT>
__global__ __launch_bounds__(512, 2) void mfma_level_kernel(
    const float* __restrict__ node_emb,
    const unsigned short* __restrict__ Bhi,
    const unsigned short* __restrict__ Blo,
    const float* __restrict__ bias,
    const float* __restrict__ h_prev,
    const float* __restrict__ c_prev,
    float* __restrict__ h_cur,
    float* __restrict__ c_cur,
    const int d, const int M)
{
    constexpr int NB = MT * 16;
    __shared__ unsigned short AhiF[8 * MT * 512];   // [kb][mt][lane*8+e]
    __shared__ unsigned short AloF[4 * MT * 512];

    const int tid  = threadIdx.x;
    const int m0   = blockIdx.x * NB;
    const bool root = (d == 0);

    // ---- stage A ----
    {
        constexpr int tpr = 512 / NB;        // threads per row (16 for MT=2)
        constexpr int nf  = 256 / tpr;       // floats per thread (16 for MT=2)
        const int r   = tid / tpr;           // 0..NB-1
        const int q   = tid % tpr;
        int gm = m0 + r;
        if (gm > M - 1) gm = M - 1;          // clamp: duplicate last row
        const int mt  = r >> 4, ml = r & 15;
        const int t     = gm >> d;
        const int p     = gm - (t << d);
        const int local = (1 << d) - 1 + p;
        const float* xrow = node_emb + (size_t)(t * NPT + local) * D_N;
        const float* hrow = root ? xrow : (h_prev + (size_t)(gm >> 1) * D_N);
        const float4 z4 = make_float4(0.f, 0.f, 0.f, 0.f);
        #pragma unroll
        for (int i = 0; i < nf / 4; ++i) {
            const int k   = q * nf + i * 4;  // no thread straddles k=128
            const int kb  = k >> 5;
            const int qk  = (k & 31) >> 3;
            const int e0  = k & 4;
            float4 v;
            if (k < 128)      v = reinterpret_cast<const float4*>(xrow)[k >> 2];
            else if (root)    v = z4;
            else              v = reinterpret_cast<const float4*>(hrow)[(k - 128) >> 2];
            const ushort4v hv = { f2bf(v.x), f2bf(v.y), f2bf(v.z), f2bf(v.w) };
            *reinterpret_cast<ushort4v*>(
                &AhiF[((kb * MT + mt) * 64 + qk * 16 + ml) * 8 + e0]) = hv;
            if (k >= 128) {
                const ushort4v lv = { f2bf(v.x - bf2f(hv.x)), f2bf(v.y - bf2f(hv.y)),
                                      f2bf(v.z - bf2f(hv.z)), f2bf(v.w - bf2f(hv.w)) };
                *reinterpret_cast<ushort4v*>(
                    &AloF[(((kb - 4) * MT + mt) * 64 + qk * 16 + ml) * 8 + e0]) = lv;
            }
        }
    }
    __syncthreads();

    const int idx  = tid >> 6;              // wave 0..7
    const int lane = tid & 63;
    const int ml   = lane & 15;
    const int quad = lane >> 4;
    const int j    = idx * 16 + ml;

    // ---- prefetch c_prev into registers (hides HBM latency under K-loop) ----
    float cpre[MT][4];
    #pragma unroll
    for (int mt = 0; mt < MT; ++mt)
        #pragma unroll
        for (int r = 0; r < 4; ++r) {
            int m = m0 + mt * 16 + quad * 4 + r;
            if (m > M - 1) m = M - 1;
            cpre[mt][r] = root ? 0.f : c_prev[(size_t)(m >> 1) * D_N + j];
        }

    f32x4 acc[MT][4];                        // [mt][gate]
    #pragma unroll
    for (int mt = 0; mt < MT; ++mt)
        #pragma unroll
        for (int g = 0; g < 4; ++g) acc[mt][g] = (f32x4)0.f;

    const short8* Bh8 = reinterpret_cast<const short8*>(Bhi);
    const short8* Bl8 = reinterpret_cast<const short8*>(Blo);
    const short8* Ah8 = reinterpret_cast<const short8*>(AhiF);
    const short8* Al8 = reinterpret_cast<const short8*>(AloF);

    short8 bh[4], bl[4];
    #pragma unroll
    for (int g = 0; g < 4; ++g)
        bh[g] = Bh8[(0 * 32 + g * 8 + idx) * 64 + lane];

    #pragma unroll
    for (int kb = 0; kb < 8; ++kb) {
        short8 bhn[4], bln[4];
        // prefetch next-kb B before issuing this kb's MFMAs
        if (kb < 7) {
            #pragma unroll
            for (int g = 0; g < 4; ++g)
                bhn[g] = Bh8[((kb + 1) * 32 + g * 8 + idx) * 64 + lane];
            if (kb + 1 >= 4) {
                #pragma unroll
                for (int g = 0; g < 4; ++g)
                    bln[g] = Bl8[((kb + 1 - 4) * 32 + g * 8 + idx) * 64 + lane];
            }
        }
        short8 ah[MT], al[MT];
        #pragma unroll
        for (int mt = 0; mt < MT; ++mt)
            ah[mt] = Ah8[(kb * MT + mt) * 64 + lane];
        if (kb >= 4) {
            #pragma unroll
            for (int mt = 0; mt < MT; ++mt)
                al[mt] = Al8[((kb - 4) * MT + mt) * 64 + lane];
        }
        #pragma unroll
        for (int g = 0; g < 4; ++g) {
            #pragma unroll
            for (int mt = 0; mt < MT; ++mt) {
                acc[mt][g] = __builtin_amdgcn_mfma_f32_16x16x32_bf16(
                    ah[mt], bh[g], acc[mt][g], 0, 0, 0);
                if (kb >= 4) {
                    acc[mt][g] = __builtin_amdgcn_mfma_f32_16x16x32_bf16(
                        ah[mt], bl[g], acc[mt][g], 0, 0, 0);
                    acc[mt][g] = __builtin_amdgcn_mfma_f32_16x16x32_bf16(
                        al[mt], bh[g], acc[mt][g], 0, 0, 0);
                }
            }
        }
        if (kb < 7) {
            #pragma unroll
            for (int g = 0; g < 4; ++g) {
                bh[g] = bhn[g];
                if (kb + 1 >= 4) bl[g] = bln[g];
            }
        }
    }

    // ---- fused LSTM epilogue (C/D: row = quad*4+r -> node, col = ml -> j) ----
    const float bi = bias[j];
    const float bf = bias[128 + j];
    const float bg = bias[256 + j];
    const float bo = bias[384 + j];
    #pragma unroll
    for (int mt = 0; mt < MT; ++mt) {
        #pragma unroll
        for (int r = 0; r < 4; ++r) {
            const int m = m0 + mt * 16 + quad * 4 + r;
            if (m < M) {
                const float ig = fsigmoid(acc[mt][0][r] + bi);
                const float fg = fsigmoid(acc[mt][1][r] + bf);
                const float gv = ftanh(acc[mt][2][r] + bg);
                const float og = fsigmoid(acc[mt][3][r] + bo);
                const float cn = fg * cpre[mt][r] + ig * gv;
                const float hn = og * ftanh(cn);
                c_cur[(size_t)m * D_N + j] = cn;
                h_cur[(size_t)m * D_N + j] = hn;
            }
        }
    }
}

// ---------------- fused leaf-extract + gather ----------------
// One 64-lane wave per (b,t) row: ballot over the one-hot cross row -> leaf,
// then out[b,t,:] = active ? h8[t*256+leaf, :] : 0   (2 floats per lane).
__global__ __launch_bounds__(256) void gather_kernel(const float* __restrict__ cross,
                                                     const float* __restrict__ h8,
                                                     float* __restrict__ out) {
    const int bt   = blockIdx.x * 4 + (threadIdx.x >> 6);
    const int lane = threadIdx.x & 63;
    const int t    = bt % T_N;
    const float4 v = reinterpret_cast<const float4*>(cross + (size_t)bt * L_N)[lane];
    int idx = -1;
    if      (v.x > 0.f) idx = lane * 4 + 0;
    else if (v.y > 0.f) idx = lane * 4 + 1;
    else if (v.z > 0.f) idx = lane * 4 + 2;
    else if (v.w > 0.f) idx = lane * 4 + 3;
    const unsigned long long m = __ballot(idx >= 0);
    int lf = -1;
    if (m != 0ULL) {
        const int first = __builtin_ctzll(m);
        lf = __shfl(idx, first);
    }
    float2 o = make_float2(0.f, 0.f);
    if (lf >= 0)
        o = reinterpret_cast<const float2*>(h8 + (size_t)(t * L_N + lf) * D_N)[lane];
    reinterpret_cast<float2*>(out + (size_t)bt * D_N)[lane] = o;
}

extern "C" void kernel_launch(void* const* d_in, const int* in_sizes, int n_in,
                              void* d_out, int out_size, void* d_ws, size_t ws_size,
                              hipStream_t stream) {
    const float* cross    = (const float*)d_in[0];
    const float* node_emb = (const float*)d_in[1];
    const float* w_ih     = (const float*)d_in[2];
    const float* w_hh     = (const float*)d_in[3];
    const float* b_ih     = (const float*)d_in[4];
    const float* b_hh     = (const float*)d_in[5];
    float* out = (float*)d_out;
    float* ws  = (float*)d_ws;

    // ws layout (floats): hA/cA (even levels, <=25600 rows),
    // hB/cB (odd levels, <=12800 rows), bias, Bhi, Blo
    const size_t SA = (size_t)25600 * D_N;
    const size_t SB = (size_t)12800 * D_N;
    float* hA = ws;
    float* cA = hA + SA;
    float* hB = cA + SA;
    float* cB = hB + SB;
    float* bias = cB + SB;
    unsigned short* Bhi = (unsigned short*)(bias + 512);
    unsigned short* Blo = Bhi + 131072;

    pack_kernel<<<512, 256, 0, stream>>>(w_ih, w_hh, b_ih, b_hh, Bhi, Blo, bias);

    // all levels 0..8 via MFMA (even d -> A buffers, odd d -> B buffers)
    for (int d = 0; d <= 8; ++d) {
        const int M = T_N << d;
        float* hc = (d & 1) ? hB : hA;
        float* cc = (d & 1) ? cB : cA;
        float* hp = (d & 1) ? hA : hB;
        float* cp = (d & 1) ? cA : cB;
        dim3 grid((M + 31) / 32);
        mfma_level_kernel<2><<<grid, 512, 0, stream>>>(node_emb, Bhi, Blo, bias,
                                                       hp, cp, hc, cc, d, M);
    }
    // d=8 wrote hA; fused leaf+gather
    gather_kernel<<<(B_N * T_N) / 4, 256, 0, stream>>>(cross, hA, out);
}